// Round 6
// baseline (477.378 us; speedup 1.0000x reference)
//
#include <hip/hip_runtime.h>
#include <hip/hip_bf16.h>

#define NN 100000
#define NE 1200000
#define IND 128
#define HID 64
#define NC 5
#define NG 128
#define NB 391    // ceil(NN/256)
#define GB 1172   // bucket blocks in fused kernel (GB*256*4 >= NE)
#define G1 3125   // gemm1 blocks (NN/32)

static __device__ __forceinline__ float bf2f(unsigned short u) {
    union { unsigned int i; float f; } x;
    x.i = (unsigned int)u << 16;
    return x.f;
}
static __device__ __forceinline__ unsigned short f2bf(float f) {
    union { float f; unsigned int i; } x;
    x.f = f;
    unsigned int r = (x.i + 0x7fffu + ((x.i >> 16) & 1u)) >> 16;  // RNE
    return (unsigned short)r;
}

// ---------------- CSR build ----------------
__global__ __launch_bounds__(256) void k_zero_int(int* __restrict__ p, int n) {
    int i = blockIdx.x * 256 + threadIdx.x;
    if (i < n) p[i] = 0;
}

__global__ __launch_bounds__(256) void k_hist(const int* __restrict__ dst, int* __restrict__ cnt,
                                              int* __restrict__ rank) {
    int e = blockIdx.x * 256 + threadIdx.x;
    if (e < NE) rank[e] = atomicAdd(&cnt[dst[e]], 1);
}

// scan over cnt + dinv = rsqrt(cnt+1) fused
__global__ __launch_bounds__(256) void k_scan1(const int* __restrict__ cnt, int* __restrict__ exc,
                                               int* __restrict__ bsum, float* __restrict__ dinv) {
    __shared__ int lds[256];
    int tid = threadIdx.x;
    int i = blockIdx.x * 256 + tid;
    int v = (i < NN) ? cnt[i] : 0;
    lds[tid] = v;
    __syncthreads();
    for (int off = 1; off < 256; off <<= 1) {
        int t = (tid >= off) ? lds[tid - off] : 0;
        __syncthreads();
        lds[tid] += t;
        __syncthreads();
    }
    if (i < NN) {
        exc[i] = lds[tid] - v;
        dinv[i] = rsqrtf((float)v + 1.0f);
    }
    if (tid == 255) bsum[blockIdx.x] = lds[255];
}

__global__ __launch_bounds__(512) void k_scan2(int* __restrict__ bsum) {
    __shared__ int lds[512];
    int tid = threadIdx.x;
    int v = (tid < NB) ? bsum[tid] : 0;
    lds[tid] = v;
    __syncthreads();
    for (int off = 1; off < 512; off <<= 1) {
        int t = (tid >= off) ? lds[tid - off] : 0;
        __syncthreads();
        lds[tid] += t;
        __syncthreads();
    }
    if (tid < NB) bsum[tid] = lds[tid] - v;
}

__global__ __launch_bounds__(256) void k_scan3(const int* __restrict__ exc, const int* __restrict__ bsum,
                                               int* __restrict__ row_ptr) {
    int i = blockIdx.x * 256 + threadIdx.x;
    if (i < NN) row_ptr[i] = exc[i] + bsum[blockIdx.x];
    if (i == 0) row_ptr[NN] = NE;
}

// ---------------- fused: bucket scatter (blocks [0,GB)) + layer-1 GEMM (blocks [GB,GB+G1)) ----------------
// gemm: out_bf[n][j] = bf16(dinv[n] * sum_k X[n][k]*W1[k][j]),  K=128, 32 nodes/block
__global__ __launch_bounds__(256) void k_gemm1_bucket(
    const float* __restrict__ X, const float* __restrict__ W,
    const float* __restrict__ dinv, unsigned short* __restrict__ out_bf,
    const int* __restrict__ src, const int* __restrict__ dst,
    const int* __restrict__ row_ptr, const int* __restrict__ rank,
    int* __restrict__ src_sorted)
{
    __shared__ float lds[IND * HID + 32 * IND];  // 48 KB: W[128][64] + x[32][128]
    int tid = threadIdx.x;

    if (blockIdx.x < GB) {
        // ---- bucket: atomic-free scatter, 4 independent edges/thread ----
        int t = blockIdx.x * 256 + tid;
        const int T = GB * 256;
#pragma unroll
        for (int u = 0; u < 4; ++u) {
            int e = t + u * T;
            if (e < NE) src_sorted[row_ptr[dst[e]] + rank[e]] = src[e];
        }
        return;
    }

    // ---- gemm1 ----
    float* Wl = lds;             // [128][64]
    float* xl = lds + IND * HID; // [32][128]
    int n0 = (blockIdx.x - GB) * 32;
    int c = tid & 31;
    int s = tid >> 5;

    {
        const float4* Wg = (const float4*)W;
        float4* Wl4 = (float4*)Wl;
#pragma unroll
        for (int i = 0; i < IND * 16 / 256; ++i) Wl4[i * 256 + tid] = Wg[i * 256 + tid];
    }
    {
        const float4* Xg = (const float4*)X;
        float4* xl4 = (float4*)xl;
        const float4 z = {0.f, 0.f, 0.f, 0.f};
#pragma unroll
        for (int i = 0; i < 32 * IND / 4 / 256; ++i) {
            int idx = i * 256 + tid;
            int node = n0 + idx / (IND / 4);
            xl4[idx] = (node < NN) ? Xg[(size_t)n0 * (IND / 4) + idx] : z;
        }
    }
    __syncthreads();

    float acc[4][2];
#pragma unroll
    for (int r = 0; r < 4; ++r) { acc[r][0] = 0.f; acc[r][1] = 0.f; }

#pragma unroll 4
    for (int k0 = 0; k0 < IND; k0 += 4) {
        float4 xv[4];
#pragma unroll
        for (int r = 0; r < 4; ++r) xv[r] = *(const float4*)&xl[(s * 4 + r) * IND + k0];
#pragma unroll
        for (int kk = 0; kk < 4; ++kk) {
            float w0 = Wl[(k0 + kk) * HID + c];
            float w1 = Wl[(k0 + kk) * HID + c + 32];
#pragma unroll
            for (int r = 0; r < 4; ++r) {
                float xe = (kk == 0) ? xv[r].x : (kk == 1) ? xv[r].y : (kk == 2) ? xv[r].z : xv[r].w;
                acc[r][0] = fmaf(xe, w0, acc[r][0]);
                acc[r][1] = fmaf(xe, w1, acc[r][1]);
            }
        }
    }

#pragma unroll
    for (int r = 0; r < 4; ++r) {
        int n = n0 + s * 4 + r;
        if (n < NN) {
            float dn = dinv[n];
            out_bf[n * HID + c]      = f2bf(acc[r][0] * dn);
            out_bf[n * HID + c + 32] = f2bf(acc[r][1] * dn);
        }
    }
}

// ---------------- fused aggregate + next-layer GEMM ----------------
// t[n] = relu(dinv[n]*(hWp[n]+sum_src hWp[src]) + bp)   (LDS, f32)
// hWn[n] = bf16(dinv[n] * (t[n] @ Wn))
__global__ __launch_bounds__(256) void k_agg_gemm(
    const unsigned short* __restrict__ hWp,
    const int* __restrict__ srcs, const int* __restrict__ row_ptr,
    const float* __restrict__ dinv, const float* __restrict__ bp,
    const float* __restrict__ Wn, unsigned short* __restrict__ hWn)
{
    __shared__ float Wl[HID * HID];  // 16 KB
    __shared__ float tl[64 * HID];   // 16 KB
    int tid = threadIdx.x;
    int n0 = blockIdx.x * 64;

    // stage Wn (loads issue before the gather; wait lands before ds_write)
    {
        const float4* Wg = (const float4*)Wn;
        float4* Wl4 = (float4*)Wl;
#pragma unroll
        for (int i = 0; i < HID * HID / 4 / 256; ++i) Wl4[i * 256 + tid] = Wg[i * 256 + tid];
    }

    // gather phase: wave w handles 16 nodes, lane = feature
    int j = tid & 63;
    int w = tid >> 6;
    for (int r = 0; r < 16; ++r) {
        int n = n0 + w * 16 + r;
        float v = 0.f;
        if (n < NN) {
            float acc = bf2f(hWp[n * HID + j]);
            int beg = row_ptr[n], end = row_ptr[n + 1];
            int e = beg;
            for (; e + 3 < end; e += 4) {
                int s0 = srcs[e], s1 = srcs[e + 1], s2 = srcs[e + 2], s3 = srcs[e + 3];
                float h0 = bf2f(hWp[s0 * HID + j]);
                float h1 = bf2f(hWp[s1 * HID + j]);
                float h2 = bf2f(hWp[s2 * HID + j]);
                float h3 = bf2f(hWp[s3 * HID + j]);
                acc += (h0 + h1) + (h2 + h3);
            }
            for (; e < end; ++e) acc += bf2f(hWp[srcs[e] * HID + j]);
            v = fmaxf(fmaf(dinv[n], acc, bp[j]), 0.f);
        }
        tl[(w * 16 + r) * HID + j] = v;
    }
    __syncthreads();

    // GEMM phase: 64 nodes x 64 cols, thread owns cols {c,c+32} x 8 nodes
    int c = tid & 31;
    int s = tid >> 5;
    float acc[8][2];
#pragma unroll
    for (int r = 0; r < 8; ++r) { acc[r][0] = 0.f; acc[r][1] = 0.f; }

#pragma unroll 4
    for (int k0 = 0; k0 < HID; k0 += 4) {
        float4 xv[8];
#pragma unroll
        for (int r = 0; r < 8; ++r) xv[r] = *(const float4*)&tl[(s * 8 + r) * HID + k0];
#pragma unroll
        for (int kk = 0; kk < 4; ++kk) {
            float w0 = Wl[(k0 + kk) * HID + c];
            float w1 = Wl[(k0 + kk) * HID + c + 32];
#pragma unroll
            for (int r = 0; r < 8; ++r) {
                float xe = (kk == 0) ? xv[r].x : (kk == 1) ? xv[r].y : (kk == 2) ? xv[r].z : xv[r].w;
                acc[r][0] = fmaf(xe, w0, acc[r][0]);
                acc[r][1] = fmaf(xe, w1, acc[r][1]);
            }
        }
    }

#pragma unroll
    for (int r = 0; r < 8; ++r) {
        int n = n0 + s * 8 + r;
        if (n < NN) {
            float dn = dinv[n];
            hWn[n * HID + c]      = f2bf(acc[r][0] * dn);
            hWn[n * HID + c + 32] = f2bf(acc[r][1] * dn);
        }
    }
}

// ---------------- layer-3 aggregate (writes f32 for pooling) ----------------
__global__ __launch_bounds__(256) void k_aggregate(const unsigned short* __restrict__ hWs,
                                                   const int* __restrict__ src_sorted,
                                                   const int* __restrict__ row_ptr,
                                                   const float* __restrict__ dinv,
                                                   const float* __restrict__ b,
                                                   float* __restrict__ out) {
    int tid = threadIdx.x;
    int j = tid & 63;
    int n = blockIdx.x * 4 + (tid >> 6);
    if (n >= NN) return;
    float acc = bf2f(hWs[n * HID + j]);
    int beg = row_ptr[n], end = row_ptr[n + 1];
    int e = beg;
    for (; e + 3 < end; e += 4) {
        int s0 = src_sorted[e], s1 = src_sorted[e + 1];
        int s2 = src_sorted[e + 2], s3 = src_sorted[e + 3];
        float h0 = bf2f(hWs[s0 * HID + j]);
        float h1 = bf2f(hWs[s1 * HID + j]);
        float h2 = bf2f(hWs[s2 * HID + j]);
        float h3 = bf2f(hWs[s3 * HID + j]);
        acc += (h0 + h1) + (h2 + h3);
    }
    for (; e < end; ++e) acc += bf2f(hWs[src_sorted[e] * HID + j]);
    out[n * HID + j] = fmaxf(fmaf(dinv[n], acc, b[j]), 0.0f);
}

// ---------------- pooling + head ----------------
__global__ __launch_bounds__(256) void k_bounds(const int* __restrict__ batch, int* __restrict__ start) {
    int i = blockIdx.x * 256 + threadIdx.x;
    if (i >= NN) return;
    int b = batch[i];
    if (i == 0) {
        for (int g = 0; g <= b; ++g) start[g] = 0;
    } else {
        int p = batch[i - 1];
        for (int g = p + 1; g <= b; ++g) start[g] = i;
    }
    if (i == NN - 1) {
        for (int g = b + 1; g <= NG; ++g) start[g] = NN;
    }
}

__global__ __launch_bounds__(256) void k_pool_head(const float* __restrict__ h, const int* __restrict__ start,
                                                   const float* __restrict__ Wc, const float* __restrict__ bc,
                                                   float* __restrict__ out) {
    __shared__ float part[4][HID];
    int g = blockIdx.x;
    int tid = threadIdx.x;
    int j = tid & 63, w = tid >> 6;
    int beg = start[g], end = start[g + 1];
    float acc = 0.0f;
    for (int n = beg + w; n < end; n += 4) acc += h[n * HID + j];
    part[w][j] = acc;
    __syncthreads();
    if (w == 0) {
        float s = part[0][j] + part[1][j] + part[2][j] + part[3][j];
        float cnt = (float)(end - beg);
        float p = s / fmaxf(cnt, 1.0f);
#pragma unroll
        for (int c = 0; c < NC; ++c) {
            float v = p * Wc[j * NC + c];
            for (int off = 32; off > 0; off >>= 1) v += __shfl_down(v, off);
            if (j == 0) out[g * NC + c] = v + bc[c];
        }
    }
}

// ---------------- driver ----------------
extern "C" void kernel_launch(void* const* d_in, const int* in_sizes, int n_in,
                              void* d_out, int out_size, void* d_ws, size_t ws_size,
                              hipStream_t stream) {
    const float* x  = (const float*)d_in[0];
    const int* ei   = (const int*)d_in[1];
    const int* bat  = (const int*)d_in[2];
    const float* W1 = (const float*)d_in[3];
    const float* b1 = (const float*)d_in[4];
    const float* W2 = (const float*)d_in[5];
    const float* b2 = (const float*)d_in[6];
    const float* W3 = (const float*)d_in[7];
    const float* b3 = (const float*)d_in[8];
    const float* Wc = (const float*)d_in[9];
    const float* bc = (const float*)d_in[10];
    float* out = (float*)d_out;

    const int* src = ei;
    const int* dst = ei + NE;

    // workspace layout (bytes). Scratch region S (cnt/exc/bsum/rank) is dead
    // before 'agg' is written, so 'agg' overlays S. Total ~56.8 MB.
    char* wsb = (char*)d_ws;
    float* dinv         = (float*)wsb;                          // 0       .. 400000
    int*   row_ptr      = (int*)(wsb + 400000);                 // 400000  .. 800004 (pad to 800016)
    int*   srcs         = (int*)(wsb + 800016);                 // 800016  .. 5600016
    unsigned short* hWA = (unsigned short*)(wsb + 5600016);     // 12.8 MB .. 18400016
    unsigned short* hWB = (unsigned short*)(wsb + 18400016);    // 12.8 MB .. 31200016
    int*   cnt          = (int*)(wsb + 31200016);               // S: NN
    int*   exc          = (int*)(wsb + 31600016);               // S: NN
    int*   bsum         = (int*)(wsb + 32000016);               // S: 512
    int*   rank         = (int*)(wsb + 32002064);               // S: NE
    float* agg          = (float*)(wsb + 31200016);             // overlays S: 25.6 MB .. 56800016
    int*   start        = (int*)(wsb + 56800016);               // NG+1

    const int gE = (NE + 255) / 256;  // 4688

    // CSR build + normalization
    k_zero_int<<<NB, 256, 0, stream>>>(cnt, NN);
    k_hist<<<gE, 256, 0, stream>>>(dst, cnt, rank);
    k_scan1<<<NB, 256, 0, stream>>>(cnt, exc, bsum, dinv);
    k_scan2<<<1, 512, 0, stream>>>(bsum);
    k_scan3<<<NB, 256, 0, stream>>>(exc, bsum, row_ptr);

    // bucket scatter overlapped with layer-1 GEMM (independent work, one grid)
    k_gemm1_bucket<<<GB + G1, 256, 0, stream>>>(x, W1, dinv, hWA, src, dst, row_ptr, rank, srcs);

    // layers 2,3: fused aggregate(prev) + GEMM(next)
    k_agg_gemm<<<(NN + 63) / 64, 256, 0, stream>>>(hWA, srcs, row_ptr, dinv, b1, W2, hWB);
    k_agg_gemm<<<(NN + 63) / 64, 256, 0, stream>>>(hWB, srcs, row_ptr, dinv, b2, W3, hWA);

    // layer-3 aggregate -> f32 for pooling
    k_aggregate<<<NN / 4, 256, 0, stream>>>(hWA, srcs, row_ptr, dinv, b3, agg);

    // pooling + head
    k_bounds<<<NB, 256, 0, stream>>>(bat, start);
    k_pool_head<<<NG, 256, 0, stream>>>(agg, start, Wc, bc, out);
}

// Round 7
// 369.475 us; speedup vs baseline: 1.2920x; 1.2920x over previous
//
#include <hip/hip_runtime.h>
#include <hip/hip_bf16.h>

#define NN 100000
#define NE 1200000
#define IND 128
#define HID 64
#define NC 5
#define NG 128
#define NB 391    // ceil(NN/256)
#define GB 1172   // bucket blocks (GB*256*4 >= NE)
#define G1 3125   // gemm1 blocks (NN/32)

static __device__ __forceinline__ float bf2f(unsigned short u) {
    union { unsigned int i; float f; } x;
    x.i = (unsigned int)u << 16;
    return x.f;
}
static __device__ __forceinline__ unsigned short f2bf(float f) {
    union { float f; unsigned int i; } x;
    x.f = f;
    unsigned int r = (x.i + 0x7fffu + ((x.i >> 16) & 1u)) >> 16;  // RNE
    return (unsigned short)r;
}

// ---------------- CSR build ----------------
__global__ __launch_bounds__(256) void k_hist(const int* __restrict__ dst, int* __restrict__ cnt,
                                              int* __restrict__ rank) {
    int e = blockIdx.x * 256 + threadIdx.x;
    if (e < NE) rank[e] = atomicAdd(&cnt[dst[e]], 1);
}

// scan over cnt + dinv = rsqrt(cnt+1) fused
__global__ __launch_bounds__(256) void k_scan1(const int* __restrict__ cnt, int* __restrict__ exc,
                                               int* __restrict__ bsum, float* __restrict__ dinv) {
    __shared__ int lds[256];
    int tid = threadIdx.x;
    int i = blockIdx.x * 256 + tid;
    int v = (i < NN) ? cnt[i] : 0;
    lds[tid] = v;
    __syncthreads();
    for (int off = 1; off < 256; off <<= 1) {
        int t = (tid >= off) ? lds[tid - off] : 0;
        __syncthreads();
        lds[tid] += t;
        __syncthreads();
    }
    if (i < NN) {
        exc[i] = lds[tid] - v;
        dinv[i] = rsqrtf((float)v + 1.0f);
    }
    if (tid == 255) bsum[blockIdx.x] = lds[255];
}

__global__ __launch_bounds__(512) void k_scan2(int* __restrict__ bsum) {
    __shared__ int lds[512];
    int tid = threadIdx.x;
    int v = (tid < NB) ? bsum[tid] : 0;
    lds[tid] = v;
    __syncthreads();
    for (int off = 1; off < 512; off <<= 1) {
        int t = (tid >= off) ? lds[tid - off] : 0;
        __syncthreads();
        lds[tid] += t;
        __syncthreads();
    }
    if (tid < NB) bsum[tid] = lds[tid] - v;
}

__global__ __launch_bounds__(256) void k_scan3(const int* __restrict__ exc, const int* __restrict__ bsum,
                                               int* __restrict__ row_ptr) {
    int i = blockIdx.x * 256 + threadIdx.x;
    if (i < NN) row_ptr[i] = exc[i] + bsum[blockIdx.x];
    if (i == 0) row_ptr[NN] = NE;
}

// ---------------- fused grid: bucket | layer-1 GEMM | bounds ----------------
__global__ __launch_bounds__(256) void k_fused1(
    const float* __restrict__ X, const float* __restrict__ W,
    const float* __restrict__ dinv, unsigned short* __restrict__ out_bf,
    const int* __restrict__ src, const int* __restrict__ dst,
    const int* __restrict__ row_ptr, const int* __restrict__ rank,
    int* __restrict__ src_sorted,
    const int* __restrict__ batch, int* __restrict__ start)
{
    __shared__ float lds[IND * HID + 32 * IND];  // 48 KB (gemm1 segment only)
    int tid = threadIdx.x;

    if (blockIdx.x < GB) {
        // ---- bucket: atomic-free scatter, 4 independent edges/thread ----
        int t = blockIdx.x * 256 + tid;
        const int T = GB * 256;
#pragma unroll
        for (int u = 0; u < 4; ++u) {
            int e = t + u * T;
            if (e < NE) src_sorted[row_ptr[dst[e]] + rank[e]] = src[e];
        }
        return;
    }
    if (blockIdx.x >= GB + G1) {
        // ---- bounds: segment starts from sorted batch ids ----
        int i = (blockIdx.x - GB - G1) * 256 + tid;
        if (i >= NN) return;
        int b = batch[i];
        if (i == 0) {
            for (int g = 0; g <= b; ++g) start[g] = 0;
        } else {
            int p = batch[i - 1];
            for (int g = p + 1; g <= b; ++g) start[g] = i;
        }
        if (i == NN - 1) {
            for (int g = b + 1; g <= NG; ++g) start[g] = NN;
        }
        return;
    }

    // ---- gemm1: out_bf[n][j] = bf16(dinv[n] * sum_k X[n][k]*W1[k][j]) ----
    float* Wl = lds;             // [128][64]
    float* xl = lds + IND * HID; // [32][128]
    int n0 = (blockIdx.x - GB) * 32;
    int c = tid & 31;
    int s = tid >> 5;

    {
        const float4* Wg = (const float4*)W;
        float4* Wl4 = (float4*)Wl;
#pragma unroll
        for (int i = 0; i < IND * 16 / 256; ++i) Wl4[i * 256 + tid] = Wg[i * 256 + tid];
    }
    {
        const float4* Xg = (const float4*)X;
        float4* xl4 = (float4*)xl;
        const float4 z = {0.f, 0.f, 0.f, 0.f};
#pragma unroll
        for (int i = 0; i < 32 * IND / 4 / 256; ++i) {
            int idx = i * 256 + tid;
            int node = n0 + idx / (IND / 4);
            xl4[idx] = (node < NN) ? Xg[(size_t)n0 * (IND / 4) + idx] : z;
        }
    }
    __syncthreads();

    float acc[4][2];
#pragma unroll
    for (int r = 0; r < 4; ++r) { acc[r][0] = 0.f; acc[r][1] = 0.f; }

#pragma unroll 4
    for (int k0 = 0; k0 < IND; k0 += 4) {
        float4 xv[4];
#pragma unroll
        for (int r = 0; r < 4; ++r) xv[r] = *(const float4*)&xl[(s * 4 + r) * IND + k0];
#pragma unroll
        for (int kk = 0; kk < 4; ++kk) {
            float w0 = Wl[(k0 + kk) * HID + c];
            float w1 = Wl[(k0 + kk) * HID + c + 32];
#pragma unroll
            for (int r = 0; r < 4; ++r) {
                float xe = (kk == 0) ? xv[r].x : (kk == 1) ? xv[r].y : (kk == 2) ? xv[r].z : xv[r].w;
                acc[r][0] = fmaf(xe, w0, acc[r][0]);
                acc[r][1] = fmaf(xe, w1, acc[r][1]);
            }
        }
    }

#pragma unroll
    for (int r = 0; r < 4; ++r) {
        int n = n0 + s * 4 + r;
        if (n < NN) {
            float dn = dinv[n];
            out_bf[n * HID + c]      = f2bf(acc[r][0] * dn);
            out_bf[n * HID + c + 32] = f2bf(acc[r][1] * dn);
        }
    }
}

// ---------------- aggregate: bf16 in, bf16 out, unroll 8/4/1 ----------------
// outb[n][j] = bf16( relu(dinv[n]*(hW[n][j] + sum_src hW[src][j]) + b[j]) )
__global__ __launch_bounds__(256) void k_aggregate(const unsigned short* __restrict__ hW,
                                                   const int* __restrict__ srcs,
                                                   const int* __restrict__ row_ptr,
                                                   const float* __restrict__ dinv,
                                                   const float* __restrict__ b,
                                                   unsigned short* __restrict__ outb) {
    int tid = threadIdx.x;
    int j = tid & 63;
    int n = blockIdx.x * 4 + (tid >> 6);
    if (n >= NN) return;
    float acc = bf2f(hW[n * HID + j]);
    int beg = row_ptr[n], end = row_ptr[n + 1];
    int e = beg;
    for (; e + 7 < end; e += 8) {
        int s0 = srcs[e],     s1 = srcs[e + 1], s2 = srcs[e + 2], s3 = srcs[e + 3];
        int s4 = srcs[e + 4], s5 = srcs[e + 5], s6 = srcs[e + 6], s7 = srcs[e + 7];
        float h0 = bf2f(hW[s0 * HID + j]);
        float h1 = bf2f(hW[s1 * HID + j]);
        float h2 = bf2f(hW[s2 * HID + j]);
        float h3 = bf2f(hW[s3 * HID + j]);
        float h4 = bf2f(hW[s4 * HID + j]);
        float h5 = bf2f(hW[s5 * HID + j]);
        float h6 = bf2f(hW[s6 * HID + j]);
        float h7 = bf2f(hW[s7 * HID + j]);
        acc += ((h0 + h1) + (h2 + h3)) + ((h4 + h5) + (h6 + h7));
    }
    if (e + 3 < end) {
        int s0 = srcs[e], s1 = srcs[e + 1], s2 = srcs[e + 2], s3 = srcs[e + 3];
        float h0 = bf2f(hW[s0 * HID + j]);
        float h1 = bf2f(hW[s1 * HID + j]);
        float h2 = bf2f(hW[s2 * HID + j]);
        float h3 = bf2f(hW[s3 * HID + j]);
        acc += (h0 + h1) + (h2 + h3);
        e += 4;
    }
    for (; e < end; ++e) acc += bf2f(hW[srcs[e] * HID + j]);
    outb[n * HID + j] = f2bf(fmaxf(fmaf(dinv[n], acc, b[j]), 0.0f));
}

// ---------------- GEMM layers 2/3: bf16 in, bf16 out ----------------
// outb[n][j] = bf16(dinv[n] * sum_k X[n][k]*W[k][j]), K=HID, 64 nodes/block
__global__ __launch_bounds__(256) void k_gemm_bf(const unsigned short* __restrict__ X,
                                                 const float* __restrict__ W,
                                                 const float* __restrict__ dinv,
                                                 unsigned short* __restrict__ outb) {
    __shared__ float Wl[HID * HID];  // 16 KB
    __shared__ float xl[64 * HID];   // 16 KB
    int tid = threadIdx.x;
    int n0 = blockIdx.x * 64;

    {
        const float4* Wg = (const float4*)W;
        float4* Wl4 = (float4*)Wl;
#pragma unroll
        for (int i = 0; i < HID * HID / 4 / 256; ++i) Wl4[i * 256 + tid] = Wg[i * 256 + tid];
    }
    // stage X: 64 rows x 128B; chunk = 16B (8 bf16)
    {
        const uint4* Xg = (const uint4*)X;
#pragma unroll
        for (int i = 0; i < 2; ++i) {
            int idx = i * 256 + tid;      // 0..511
            int ln = idx >> 3;            // local node
            int k0 = (idx & 7) * 8;
            int node = n0 + ln;
            float f[8];
            if (node < NN) {
                uint4 u = Xg[(size_t)n0 * 8 + idx];
                f[0] = bf2f((unsigned short)(u.x & 0xffff));
                f[1] = bf2f((unsigned short)(u.x >> 16));
                f[2] = bf2f((unsigned short)(u.y & 0xffff));
                f[3] = bf2f((unsigned short)(u.y >> 16));
                f[4] = bf2f((unsigned short)(u.z & 0xffff));
                f[5] = bf2f((unsigned short)(u.z >> 16));
                f[6] = bf2f((unsigned short)(u.w & 0xffff));
                f[7] = bf2f((unsigned short)(u.w >> 16));
            } else {
#pragma unroll
                for (int q = 0; q < 8; ++q) f[q] = 0.f;
            }
#pragma unroll
            for (int q = 0; q < 8; ++q) xl[ln * HID + k0 + q] = f[q];
        }
    }
    __syncthreads();

    int c = tid & 31;
    int s = tid >> 5;
    float acc[8][2];
#pragma unroll
    for (int r = 0; r < 8; ++r) { acc[r][0] = 0.f; acc[r][1] = 0.f; }

#pragma unroll 4
    for (int k0 = 0; k0 < HID; k0 += 4) {
        float4 xv[8];
#pragma unroll
        for (int r = 0; r < 8; ++r) xv[r] = *(const float4*)&xl[(s * 8 + r) * HID + k0];
#pragma unroll
        for (int kk = 0; kk < 4; ++kk) {
            float w0 = Wl[(k0 + kk) * HID + c];
            float w1 = Wl[(k0 + kk) * HID + c + 32];
#pragma unroll
            for (int r = 0; r < 8; ++r) {
                float xe = (kk == 0) ? xv[r].x : (kk == 1) ? xv[r].y : (kk == 2) ? xv[r].z : xv[r].w;
                acc[r][0] = fmaf(xe, w0, acc[r][0]);
                acc[r][1] = fmaf(xe, w1, acc[r][1]);
            }
        }
    }

#pragma unroll
    for (int r = 0; r < 8; ++r) {
        int n = n0 + s * 8 + r;
        if (n < NN) {
            float dn = dinv[n];
            outb[n * HID + c]      = f2bf(acc[r][0] * dn);
            outb[n * HID + c + 32] = f2bf(acc[r][1] * dn);
        }
    }
}

// ---------------- pooling + head (bf16 input) ----------------
__global__ __launch_bounds__(256) void k_pool_head(const unsigned short* __restrict__ h,
                                                   const int* __restrict__ start,
                                                   const float* __restrict__ Wc, const float* __restrict__ bc,
                                                   float* __restrict__ out) {
    __shared__ float part[4][HID];
    int g = blockIdx.x;
    int tid = threadIdx.x;
    int j = tid & 63, w = tid >> 6;
    int beg = start[g], end = start[g + 1];
    float acc = 0.0f;
    for (int n = beg + w; n < end; n += 4) acc += bf2f(h[n * HID + j]);
    part[w][j] = acc;
    __syncthreads();
    if (w == 0) {
        float s = part[0][j] + part[1][j] + part[2][j] + part[3][j];
        float cnt = (float)(end - beg);
        float p = s / fmaxf(cnt, 1.0f);
#pragma unroll
        for (int c = 0; c < NC; ++c) {
            float v = p * Wc[j * NC + c];
            for (int off = 32; off > 0; off >>= 1) v += __shfl_down(v, off);
            if (j == 0) out[g * NC + c] = v + bc[c];
        }
    }
}

// ---------------- driver ----------------
extern "C" void kernel_launch(void* const* d_in, const int* in_sizes, int n_in,
                              void* d_out, int out_size, void* d_ws, size_t ws_size,
                              hipStream_t stream) {
    const float* x  = (const float*)d_in[0];
    const int* ei   = (const int*)d_in[1];
    const int* bat  = (const int*)d_in[2];
    const float* W1 = (const float*)d_in[3];
    const float* b1 = (const float*)d_in[4];
    const float* W2 = (const float*)d_in[5];
    const float* b2 = (const float*)d_in[6];
    const float* W3 = (const float*)d_in[7];
    const float* b3 = (const float*)d_in[8];
    const float* Wc = (const float*)d_in[9];
    const float* bc = (const float*)d_in[10];
    float* out = (float*)d_out;

    const int* src = ei;
    const int* dst = ei + NE;

    // workspace layout (bytes), all 16B-aligned; total ~36.9 MB
    char* wsb = (char*)d_ws;
    float* dinv         = (float*)wsb;                          // NN f32
    int*   row_ptr      = (int*)(wsb + 400000);                 // NN+1
    int*   srcs         = (int*)(wsb + 800016);                 // NE
    unsigned short* hWA = (unsigned short*)(wsb + 5600016);     // NN*HID bf16
    unsigned short* hWB = (unsigned short*)(wsb + 18400016);    // NN*HID bf16
    int*   cnt          = (int*)(wsb + 31200016);               // NN
    int*   exc          = (int*)(wsb + 31600016);               // NN
    int*   bsum         = (int*)(wsb + 32000016);               // 512
    int*   rank         = (int*)(wsb + 32002064);               // NE
    int*   start        = (int*)(wsb + 36802064);               // NG+1

    const int gE = (NE + 255) / 256;  // 4688

    // CSR build + normalization
    hipMemsetAsync(cnt, 0, NN * sizeof(int), stream);
    k_hist<<<gE, 256, 0, stream>>>(dst, cnt, rank);
    k_scan1<<<NB, 256, 0, stream>>>(cnt, exc, bsum, dinv);
    k_scan2<<<1, 512, 0, stream>>>(bsum);
    k_scan3<<<NB, 256, 0, stream>>>(exc, bsum, row_ptr);

    // bucket scatter + layer-1 GEMM + pool bounds, one grid (independent work)
    k_fused1<<<GB + G1 + NB, 256, 0, stream>>>(x, W1, dinv, hWA, src, dst, row_ptr, rank, srcs, bat, start);

    // layers (ping-pong bf16 buffers)
    k_aggregate<<<NN / 4, 256, 0, stream>>>(hWA, srcs, row_ptr, dinv, b1, hWB);
    k_gemm_bf<<<(NN + 63) / 64, 256, 0, stream>>>(hWB, W2, dinv, hWA);
    k_aggregate<<<NN / 4, 256, 0, stream>>>(hWA, srcs, row_ptr, dinv, b2, hWB);
    k_gemm_bf<<<(NN + 63) / 64, 256, 0, stream>>>(hWB, W3, dinv, hWA);
    k_aggregate<<<NN / 4, 256, 0, stream>>>(hWA, srcs, row_ptr, dinv, b3, hWB);

    // pooling + head
    k_pool_head<<<NG, 256, 0, stream>>>(hWB, start, Wc, bc, out);
}

// Round 8
// 353.510 us; speedup vs baseline: 1.3504x; 1.0452x over previous
//
#include <hip/hip_runtime.h>
#include <hip/hip_bf16.h>

#define NN 100000
#define NE 1200000
#define IND 128
#define HID 64
#define NC 5
#define NG 128
#define NB 391    // ceil(NN/256)
#define GB 1172   // bucket blocks (GB*256*4 >= NE)
#define G1 3125   // gemm1 blocks (NN/32)

static __device__ __forceinline__ float bf2f(unsigned short u) {
    union { unsigned int i; float f; } x;
    x.i = (unsigned int)u << 16;
    return x.f;
}
static __device__ __forceinline__ unsigned short f2bf(float f) {
    union { float f; unsigned int i; } x;
    x.f = f;
    unsigned int r = (x.i + 0x7fffu + ((x.i >> 16) & 1u)) >> 16;  // RNE
    return (unsigned short)r;
}

// ---------------- CSR build ----------------
__global__ __launch_bounds__(256) void k_hist(const int* __restrict__ dst, int* __restrict__ cnt,
                                              int* __restrict__ rank) {
    int e = blockIdx.x * 256 + threadIdx.x;
    if (e < NE) rank[e] = atomicAdd(&cnt[dst[e]], 1);
}

// scan over cnt + dinv = rsqrt(cnt+1) fused
__global__ __launch_bounds__(256) void k_scan1(const int* __restrict__ cnt, int* __restrict__ exc,
                                               int* __restrict__ bsum, float* __restrict__ dinv) {
    __shared__ int lds[256];
    int tid = threadIdx.x;
    int i = blockIdx.x * 256 + tid;
    int v = (i < NN) ? cnt[i] : 0;
    lds[tid] = v;
    __syncthreads();
    for (int off = 1; off < 256; off <<= 1) {
        int t = (tid >= off) ? lds[tid - off] : 0;
        __syncthreads();
        lds[tid] += t;
        __syncthreads();
    }
    if (i < NN) {
        exc[i] = lds[tid] - v;
        dinv[i] = rsqrtf((float)v + 1.0f);
    }
    if (tid == 255) bsum[blockIdx.x] = lds[255];
}

// merged scan2+scan3: each block computes prefix(bsum[0..blockIdx.x)) by reduction
__global__ __launch_bounds__(256) void k_scan23(const int* __restrict__ exc, const int* __restrict__ bsum,
                                                int* __restrict__ row_ptr) {
    __shared__ int lds[256];
    int tid = threadIdx.x;
    int me = blockIdx.x;
    int v = 0;
    if (tid < me) v = bsum[tid];
    if (tid + 256 < me) v += bsum[tid + 256];
    lds[tid] = v;
    __syncthreads();
    for (int off = 128; off > 0; off >>= 1) {
        if (tid < off) lds[tid] += lds[tid + off];
        __syncthreads();
    }
    int base = lds[0];
    int i = me * 256 + tid;
    if (i < NN) row_ptr[i] = exc[i] + base;
    if (i == 0) row_ptr[NN] = NE;
}

// ---------------- fused grid: bucket | layer-1 GEMM | bounds ----------------
__global__ __launch_bounds__(256) void k_fused1(
    const float* __restrict__ X, const float* __restrict__ W,
    const float* __restrict__ dinv, unsigned short* __restrict__ out_bf,
    const int* __restrict__ src, const int* __restrict__ dst,
    const int* __restrict__ row_ptr, const int* __restrict__ rank,
    int* __restrict__ src_sorted,
    const int* __restrict__ batch, int* __restrict__ start)
{
    __shared__ float lds[IND * HID + 32 * IND];  // 48 KB (gemm1 segment only)
    int tid = threadIdx.x;

    if (blockIdx.x < GB) {
        // ---- bucket: atomic-free scatter, 4 independent edges/thread ----
        int t = blockIdx.x * 256 + tid;
        const int T = GB * 256;
#pragma unroll
        for (int u = 0; u < 4; ++u) {
            int e = t + u * T;
            if (e < NE) src_sorted[row_ptr[dst[e]] + rank[e]] = src[e];
        }
        return;
    }
    if (blockIdx.x >= GB + G1) {
        // ---- bounds: segment starts from sorted batch ids ----
        int i = (blockIdx.x - GB - G1) * 256 + tid;
        if (i >= NN) return;
        int b = batch[i];
        if (i == 0) {
            for (int g = 0; g <= b; ++g) start[g] = 0;
        } else {
            int p = batch[i - 1];
            for (int g = p + 1; g <= b; ++g) start[g] = i;
        }
        if (i == NN - 1) {
            for (int g = b + 1; g <= NG; ++g) start[g] = NN;
        }
        return;
    }

    // ---- gemm1: out_bf[n][j] = bf16(dinv[n] * sum_k X[n][k]*W1[k][j]) ----
    float* Wl = lds;             // [128][64]
    float* xl = lds + IND * HID; // [32][128]
    int n0 = (blockIdx.x - GB) * 32;
    int c = tid & 31;
    int s = tid >> 5;

    {
        const float4* Wg = (const float4*)W;
        float4* Wl4 = (float4*)Wl;
#pragma unroll
        for (int i = 0; i < IND * 16 / 256; ++i) Wl4[i * 256 + tid] = Wg[i * 256 + tid];
    }
    {
        const float4* Xg = (const float4*)X;
        float4* xl4 = (float4*)xl;
        const float4 z = {0.f, 0.f, 0.f, 0.f};
#pragma unroll
        for (int i = 0; i < 32 * IND / 4 / 256; ++i) {
            int idx = i * 256 + tid;
            int node = n0 + idx / (IND / 4);
            xl4[idx] = (node < NN) ? Xg[(size_t)n0 * (IND / 4) + idx] : z;
        }
    }
    __syncthreads();

    float acc[4][2];
#pragma unroll
    for (int r = 0; r < 4; ++r) { acc[r][0] = 0.f; acc[r][1] = 0.f; }

#pragma unroll 4
    for (int k0 = 0; k0 < IND; k0 += 4) {
        float4 xv[4];
#pragma unroll
        for (int r = 0; r < 4; ++r) xv[r] = *(const float4*)&xl[(s * 4 + r) * IND + k0];
#pragma unroll
        for (int kk = 0; kk < 4; ++kk) {
            float w0 = Wl[(k0 + kk) * HID + c];
            float w1 = Wl[(k0 + kk) * HID + c + 32];
#pragma unroll
            for (int r = 0; r < 4; ++r) {
                float xe = (kk == 0) ? xv[r].x : (kk == 1) ? xv[r].y : (kk == 2) ? xv[r].z : xv[r].w;
                acc[r][0] = fmaf(xe, w0, acc[r][0]);
                acc[r][1] = fmaf(xe, w1, acc[r][1]);
            }
        }
    }

#pragma unroll
    for (int r = 0; r < 4; ++r) {
        int n = n0 + s * 4 + r;
        if (n < NN) {
            float dn = dinv[n];
            out_bf[n * HID + c]      = f2bf(acc[r][0] * dn);
            out_bf[n * HID + c + 32] = f2bf(acc[r][1] * dn);
        }
    }
}

// drain helper: unroll 8/4/1 over [e,end)
static __device__ __forceinline__ float gather_drain(const unsigned short* __restrict__ hW,
                                                     const int* __restrict__ srcs,
                                                     int e, int end, int j) {
    float acc = 0.f;
    for (; e + 7 < end; e += 8) {
        int s0 = srcs[e],     s1 = srcs[e + 1], s2 = srcs[e + 2], s3 = srcs[e + 3];
        int s4 = srcs[e + 4], s5 = srcs[e + 5], s6 = srcs[e + 6], s7 = srcs[e + 7];
        float h0 = bf2f(hW[s0 * HID + j]);
        float h1 = bf2f(hW[s1 * HID + j]);
        float h2 = bf2f(hW[s2 * HID + j]);
        float h3 = bf2f(hW[s3 * HID + j]);
        float h4 = bf2f(hW[s4 * HID + j]);
        float h5 = bf2f(hW[s5 * HID + j]);
        float h6 = bf2f(hW[s6 * HID + j]);
        float h7 = bf2f(hW[s7 * HID + j]);
        acc += ((h0 + h1) + (h2 + h3)) + ((h4 + h5) + (h6 + h7));
    }
    if (e + 3 < end) {
        int s0 = srcs[e], s1 = srcs[e + 1], s2 = srcs[e + 2], s3 = srcs[e + 3];
        float h0 = bf2f(hW[s0 * HID + j]);
        float h1 = bf2f(hW[s1 * HID + j]);
        float h2 = bf2f(hW[s2 * HID + j]);
        float h3 = bf2f(hW[s3 * HID + j]);
        acc += (h0 + h1) + (h2 + h3);
        e += 4;
    }
    for (; e < end; ++e) acc += bf2f(hW[srcs[e] * HID + j]);
    return acc;
}

// ---------------- aggregate: 2 nodes per wave, interleaved 4+4 gather streams ----------------
// outb[n][j] = bf16( relu(dinv[n]*(hW[n][j] + sum_src hW[src][j]) + b[j]) )
__global__ __launch_bounds__(256) void k_aggregate(const unsigned short* __restrict__ hW,
                                                   const int* __restrict__ srcs,
                                                   const int* __restrict__ row_ptr,
                                                   const float* __restrict__ dinv,
                                                   const float* __restrict__ b,
                                                   unsigned short* __restrict__ outb) {
    int tid = threadIdx.x;
    int j = tid & 63;
    int nA = blockIdx.x * 8 + (tid >> 6) * 2;  // NN = 12500*8, always valid
    int nB = nA + 1;

    float accA = bf2f(hW[nA * HID + j]);
    float accB = bf2f(hW[nB * HID + j]);
    int eA = row_ptr[nA];
    int ea = row_ptr[nA + 1];   // == row_ptr[nB]
    int eB = ea;
    int eb = row_ptr[nB + 1];

    // interleaved main loop: 8 gathers in flight across two independent streams
    while (eA + 3 < ea && eB + 3 < eb) {
        int a0 = srcs[eA], a1 = srcs[eA + 1], a2 = srcs[eA + 2], a3 = srcs[eA + 3];
        int b0 = srcs[eB], b1 = srcs[eB + 1], b2 = srcs[eB + 2], b3 = srcs[eB + 3];
        float hA0 = bf2f(hW[a0 * HID + j]);
        float hA1 = bf2f(hW[a1 * HID + j]);
        float hA2 = bf2f(hW[a2 * HID + j]);
        float hA3 = bf2f(hW[a3 * HID + j]);
        float hB0 = bf2f(hW[b0 * HID + j]);
        float hB1 = bf2f(hW[b1 * HID + j]);
        float hB2 = bf2f(hW[b2 * HID + j]);
        float hB3 = bf2f(hW[b3 * HID + j]);
        accA += (hA0 + hA1) + (hA2 + hA3);
        accB += (hB0 + hB1) + (hB2 + hB3);
        eA += 4; eB += 4;
    }
    accA += gather_drain(hW, srcs, eA, ea, j);
    accB += gather_drain(hW, srcs, eB, eb, j);

    float bj = b[j];
    outb[nA * HID + j] = f2bf(fmaxf(fmaf(dinv[nA], accA, bj), 0.0f));
    outb[nB * HID + j] = f2bf(fmaxf(fmaf(dinv[nB], accB, bj), 0.0f));
}

// ---------------- GEMM layers 2/3: bf16 in, bf16 out ----------------
__global__ __launch_bounds__(256) void k_gemm_bf(const unsigned short* __restrict__ X,
                                                 const float* __restrict__ W,
                                                 const float* __restrict__ dinv,
                                                 unsigned short* __restrict__ outb) {
    __shared__ float Wl[HID * HID];  // 16 KB
    __shared__ float xl[64 * HID];   // 16 KB
    int tid = threadIdx.x;
    int n0 = blockIdx.x * 64;

    {
        const float4* Wg = (const float4*)W;
        float4* Wl4 = (float4*)Wl;
#pragma unroll
        for (int i = 0; i < HID * HID / 4 / 256; ++i) Wl4[i * 256 + tid] = Wg[i * 256 + tid];
    }
    {
        const uint4* Xg = (const uint4*)X;
#pragma unroll
        for (int i = 0; i < 2; ++i) {
            int idx = i * 256 + tid;      // 0..511
            int ln = idx >> 3;            // local node
            int k0 = (idx & 7) * 8;
            int node = n0 + ln;
            float f[8];
            if (node < NN) {
                uint4 u = Xg[(size_t)n0 * 8 + idx];
                f[0] = bf2f((unsigned short)(u.x & 0xffff));
                f[1] = bf2f((unsigned short)(u.x >> 16));
                f[2] = bf2f((unsigned short)(u.y & 0xffff));
                f[3] = bf2f((unsigned short)(u.y >> 16));
                f[4] = bf2f((unsigned short)(u.z & 0xffff));
                f[5] = bf2f((unsigned short)(u.z >> 16));
                f[6] = bf2f((unsigned short)(u.w & 0xffff));
                f[7] = bf2f((unsigned short)(u.w >> 16));
            } else {
#pragma unroll
                for (int q = 0; q < 8; ++q) f[q] = 0.f;
            }
#pragma unroll
            for (int q = 0; q < 8; ++q) xl[ln * HID + k0 + q] = f[q];
        }
    }
    __syncthreads();

    int c = tid & 31;
    int s = tid >> 5;
    float acc[8][2];
#pragma unroll
    for (int r = 0; r < 8; ++r) { acc[r][0] = 0.f; acc[r][1] = 0.f; }

#pragma unroll 4
    for (int k0 = 0; k0 < HID; k0 += 4) {
        float4 xv[8];
#pragma unroll
        for (int r = 0; r < 8; ++r) xv[r] = *(const float4*)&xl[(s * 8 + r) * HID + k0];
#pragma unroll
        for (int kk = 0; kk < 4; ++kk) {
            float w0 = Wl[(k0 + kk) * HID + c];
            float w1 = Wl[(k0 + kk) * HID + c + 32];
#pragma unroll
            for (int r = 0; r < 8; ++r) {
                float xe = (kk == 0) ? xv[r].x : (kk == 1) ? xv[r].y : (kk == 2) ? xv[r].z : xv[r].w;
                acc[r][0] = fmaf(xe, w0, acc[r][0]);
                acc[r][1] = fmaf(xe, w1, acc[r][1]);
            }
        }
    }

#pragma unroll
    for (int r = 0; r < 8; ++r) {
        int n = n0 + s * 8 + r;
        if (n < NN) {
            float dn = dinv[n];
            outb[n * HID + c]      = f2bf(acc[r][0] * dn);
            outb[n * HID + c + 32] = f2bf(acc[r][1] * dn);
        }
    }
}

// ---------------- pooling + head (bf16 input) ----------------
__global__ __launch_bounds__(256) void k_pool_head(const unsigned short* __restrict__ h,
                                                   const int* __restrict__ start,
                                                   const float* __restrict__ Wc, const float* __restrict__ bc,
                                                   float* __restrict__ out) {
    __shared__ float part[4][HID];
    int g = blockIdx.x;
    int tid = threadIdx.x;
    int j = tid & 63, w = tid >> 6;
    int beg = start[g], end = start[g + 1];
    float acc = 0.0f;
    for (int n = beg + w; n < end; n += 4) acc += bf2f(h[n * HID + j]);
    part[w][j] = acc;
    __syncthreads();
    if (w == 0) {
        float s = part[0][j] + part[1][j] + part[2][j] + part[3][j];
        float cnt = (float)(end - beg);
        float p = s / fmaxf(cnt, 1.0f);
#pragma unroll
        for (int c = 0; c < NC; ++c) {
            float v = p * Wc[j * NC + c];
            for (int off = 32; off > 0; off >>= 1) v += __shfl_down(v, off);
            if (j == 0) out[g * NC + c] = v + bc[c];
        }
    }
}

// ---------------- driver ----------------
extern "C" void kernel_launch(void* const* d_in, const int* in_sizes, int n_in,
                              void* d_out, int out_size, void* d_ws, size_t ws_size,
                              hipStream_t stream) {
    const float* x  = (const float*)d_in[0];
    const int* ei   = (const int*)d_in[1];
    const int* bat  = (const int*)d_in[2];
    const float* W1 = (const float*)d_in[3];
    const float* b1 = (const float*)d_in[4];
    const float* W2 = (const float*)d_in[5];
    const float* b2 = (const float*)d_in[6];
    const float* W3 = (const float*)d_in[7];
    const float* b3 = (const float*)d_in[8];
    const float* Wc = (const float*)d_in[9];
    const float* bc = (const float*)d_in[10];
    float* out = (float*)d_out;

    const int* src = ei;
    const int* dst = ei + NE;

    // workspace layout (bytes), all 16B-aligned; total ~36.9 MB
    char* wsb = (char*)d_ws;
    float* dinv         = (float*)wsb;                          // NN f32
    int*   row_ptr      = (int*)(wsb + 400000);                 // NN+1
    int*   srcs         = (int*)(wsb + 800016);                 // NE
    unsigned short* hWA = (unsigned short*)(wsb + 5600016);     // NN*HID bf16
    unsigned short* hWB = (unsigned short*)(wsb + 18400016);    // NN*HID bf16
    int*   cnt          = (int*)(wsb + 31200016);               // NN
    int*   exc          = (int*)(wsb + 31600016);               // NN
    int*   bsum         = (int*)(wsb + 32000016);               // 512
    int*   rank         = (int*)(wsb + 32002064);               // NE
    int*   start        = (int*)(wsb + 36802064);               // NG+1

    const int gE = (NE + 255) / 256;  // 4688

    // CSR build + normalization
    hipMemsetAsync(cnt, 0, NN * sizeof(int), stream);
    k_hist<<<gE, 256, 0, stream>>>(dst, cnt, rank);
    k_scan1<<<NB, 256, 0, stream>>>(cnt, exc, bsum, dinv);
    k_scan23<<<NB, 256, 0, stream>>>(exc, bsum, row_ptr);

    // bucket scatter + layer-1 GEMM + pool bounds, one grid (independent work)
    k_fused1<<<GB + G1 + NB, 256, 0, stream>>>(x, W1, dinv, hWA, src, dst, row_ptr, rank, srcs, bat, start);

    // layers (ping-pong bf16 buffers)
    k_aggregate<<<NN / 8, 256, 0, stream>>>(hWA, srcs, row_ptr, dinv, b1, hWB);
    k_gemm_bf<<<(NN + 63) / 64, 256, 0, stream>>>(hWB, W2, dinv, hWA);
    k_aggregate<<<NN / 8, 256, 0, stream>>>(hWA, srcs, row_ptr, dinv, b2, hWB);
    k_gemm_bf<<<(NN + 63) / 64, 256, 0, stream>>>(hWB, W3, dinv, hWA);
    k_aggregate<<<NN / 8, 256, 0, stream>>>(hWA, srcs, row_ptr, dinv, b3, hWB);

    // pooling + head
    k_pool_head<<<NG, 256, 0, stream>>>(hWB, start, Wc, bc, out);
}